// Round 6
// baseline (526.807 us; speedup 1.0000x reference)
//
#include <hip/hip_runtime.h>

// out[b, n] = sum_k x[b,k] * w[n,k];  B=8, K=4096, N=11008, fp32.
// HBM floor: 180.4 MB weight / 6.3 TB/s ~= 29 us. Harness adds ~165 us/iter.
// Round-6: persistent grid (256 blocks = 1/CU via 128 KB LDS), stage ALL of x
// into LDS once, ONE barrier, then each wave streams whole 16 KB weight rows
// (stride 2048). Per 1 KB step: 1 global f32x4 load + 8 conflict-free
// ds_read_b128 + 32 FMA; the 16-step row is fully unrolled so many weight
// loads stay in flight. Zero barriers / zero cross-wave traffic in hot loop.
// R5 lesson applied: per-block weight consumed (~690 KB) >> staging (128 KB).

typedef float f32x4 __attribute__((ext_vector_type(4)));

#define BATCH 8
#define KDIM  4096
#define NDIM  11008
#define K4    (KDIM / 4)          // 1024 f32x4 per row
#define BLOCK 512                 // 8 waves
#define GRID  256                 // persistent: one block per CU
#define NWAVES (GRID * BLOCK / 64)  // 2048 waves total

__global__ __launch_bounds__(BLOCK)
void ActivationSparseLinear_4982162063725_kernel(const float* __restrict__ x,
                                                 const float* __restrict__ w,
                                                 float* __restrict__ out) {
    __shared__ f32x4 xs[BATCH * K4];          // 8192 f32x4 = 128 KB (all of x)

    const int tid  = threadIdx.x;
    const int lane = tid & 63;
    const int wave = tid >> 6;

    const f32x4* x4 = (const f32x4*)x;        // [BATCH][K4], contiguous 128 KB
    const f32x4* w4 = (const f32x4*)w;        // [NDIM][K4]

    // Stage all of x: 8192 f32x4 over 512 threads = 16 coalesced passes.
#pragma unroll
    for (int i = 0; i < (BATCH * K4) / BLOCK; ++i)
        xs[i * BLOCK + tid] = x4[i * BLOCK + tid];
    __syncthreads();                          // the ONLY barrier

    const int wgid = blockIdx.x * (BLOCK / 64) + wave;   // 0..2047

    for (int n = wgid; n < NDIM; n += NWAVES) {
        const f32x4* wrow = w4 + (size_t)n * K4;

        float acc[BATCH];
#pragma unroll
        for (int b = 0; b < BATCH; ++b) acc[b] = 0.0f;

        // One full 16 KB row per wave: 16 sequential 1 KB wave-loads,
        // fully unrolled so loads pipeline deep ahead of their FMAs.
#pragma unroll
        for (int j = 0; j < K4 / 64; ++j) {
            const f32x4 wv = wrow[j * 64 + lane];
#pragma unroll
            for (int b = 0; b < BATCH; ++b) {
                const f32x4 xv = xs[b * K4 + j * 64 + lane];
                acc[b] += wv.x * xv.x + wv.y * xv.y + wv.z * xv.z + wv.w * xv.w;
            }
        }

        // Wave-private butterfly reduction; lane 0 stores the 8 outputs.
#pragma unroll
        for (int b = 0; b < BATCH; ++b) {
            float v = acc[b];
#pragma unroll
            for (int off = 32; off > 0; off >>= 1)
                v += __shfl_xor(v, off, 64);
            if (lane == 0)
                out[(size_t)b * NDIM + n] = v;
        }
    }
}

extern "C" void kernel_launch(void* const* d_in, const int* in_sizes, int n_in,
                              void* d_out, int out_size, void* d_ws, size_t ws_size,
                              hipStream_t stream) {
    const float* x = (const float*)d_in[0];   // (8, 1, 4096) fp32
    const float* w = (const float*)d_in[1];   // (11008, 4096) fp32
    float* out = (float*)d_out;               // (8, 1, 11008) fp32

    ActivationSparseLinear_4982162063725_kernel<<<GRID, BLOCK, 0, stream>>>(x, w, out);
}